// Round 9
// baseline (1333.351 us; speedup 1.0000x reference)
//
#include <hip/hip_runtime.h>

// ---------------- problem constants ----------------
#define B_    2
#define S_    2048
#define HID_  3584
#define NH_   16
#define NKV_  8
#define HD_   256
#define DQ_   (NH_ * HD_)    // 4096
#define DKV_  (NKV_ * HD_)   // 2048

static constexpr float SCALE_ = 0.0625f;   // 256^-0.5

typedef __bf16 bf16_t;
typedef __bf16 bf16x8 __attribute__((ext_vector_type(8)));
typedef __bf16 bf16x4 __attribute__((ext_vector_type(4)));
typedef float  f32x4  __attribute__((ext_vector_type(4)));

// ---------------- f32 -> bf16 convert ----------------
__global__ __launch_bounds__(256) void cvt_kernel(const float* __restrict__ in,
                                                  bf16_t* __restrict__ out, int n4) {
  int i = blockIdx.x * 256 + threadIdx.x;
  if (i < n4) {
    float4 v = ((const float4*)in)[i];
    bf16x4 o;
    o[0] = (bf16_t)v.x; o[1] = (bf16_t)v.y; o[2] = (bf16_t)v.z; o[3] = (bf16_t)v.w;
    ((bf16x4*)out)[i] = o;
  }
}

// ---------------- async global->LDS, 16B per lane ----------------
__device__ inline void gload_lds16(const bf16_t* g, bf16_t* l) {
  __builtin_amdgcn_global_load_lds(
      (const __attribute__((address_space(1))) void*)g,
      (__attribute__((address_space(3))) void*)l, 16, 0, 0);
}

// ---------------- GEMM (m97 structure): C[m][n] = sum_k A[m][k]*Bt[n][k], both bf16 ----------------
// MODE 0: OUT f32, plain row-major [M][N]          (o-proj -> d_out)
// MODE 1: OUT bf16, relayout to (B, nh, S, HD)     (Q, K projections)
// MODE 2: OUT bf16, transpose to (B, NKV, HD, S)   (V projection)
template<int MODE>
__global__ __launch_bounds__(256) void gemm_lds(const bf16_t* __restrict__ A,
                                                const bf16_t* __restrict__ Bt,
                                                void* __restrict__ outv,
                                                int M, int N, int K, int nh) {
  __shared__ __align__(16) bf16_t As[128 * 32];
  __shared__ __align__(16) bf16_t Bs[128 * 32];
  const int t = threadIdx.x;
  const int lane = t & 63, wv = t >> 6;
  const int wr = wv >> 1, wc = wv & 1;
  const int lr = lane & 15, lg = lane >> 4;
  const size_t m0 = (size_t)blockIdx.y * 128, n0 = (size_t)blockIdx.x * 128;

  const int srow = wv * 32 + (lane >> 2);
  const int scol = (lane & 3) * 8;
  const bf16_t* ga0 = A  + (m0 + srow) * (size_t)K + scol;
  const bf16_t* gb0 = Bt + (n0 + srow) * (size_t)K + scol;
  bf16_t* la0 = &As[wv * 1024];        // wave-uniform LDS bases
  bf16_t* la1 = &As[wv * 1024 + 512];
  bf16_t* lb0 = &Bs[wv * 1024];
  bf16_t* lb1 = &Bs[wv * 1024 + 512];
  const size_t k16 = 16 * (size_t)K;

  f32x4 acc[4][4] = {};
  for (int k0 = 0; k0 < K; k0 += 32) {
    __syncthreads();
    gload_lds16(ga0 + k0,       la0);
    gload_lds16(ga0 + k16 + k0, la1);
    gload_lds16(gb0 + k0,       lb0);
    gload_lds16(gb0 + k16 + k0, lb1);
    __syncthreads();

    bf16x8 af[4], bfr[4];
#pragma unroll
    for (int i = 0; i < 4; ++i) af[i]  = *(const bf16x8*)&As[(wr * 64 + i * 16 + lr) * 32 + lg * 8];
#pragma unroll
    for (int j = 0; j < 4; ++j) bfr[j] = *(const bf16x8*)&Bs[(wc * 64 + j * 16 + lr) * 32 + lg * 8];
#pragma unroll
    for (int i = 0; i < 4; ++i)
#pragma unroll
      for (int j = 0; j < 4; ++j)
        acc[i][j] = __builtin_amdgcn_mfma_f32_16x16x32_bf16(af[i], bfr[j], acc[i][j], 0, 0, 0);
  }
#pragma unroll
  for (int i = 0; i < 4; ++i)
#pragma unroll
    for (int j = 0; j < 4; ++j) {
      const int row0 = (int)m0 + wr * 64 + i * 16 + lg * 4;
      const int col  = (int)n0 + wc * 64 + j * 16 + lr;
#pragma unroll
      for (int r = 0; r < 4; ++r) {
        const int row = row0 + r;
        if (MODE == 0) {
          ((float*)outv)[(size_t)row * N + col] = acc[i][j][r];
        } else {
          bf16_t* out = (bf16_t*)outv;
          const bf16_t val = (bf16_t)acc[i][j][r];
          const int b = row >> 11, s = row & (S_ - 1);
          const int h = col >> 8,  hd = col & (HD_ - 1);
          if (MODE == 1) out[((size_t)(b * nh + h) * S_ + s) * HD_ + hd] = val;
          else           out[((size_t)(b * NKV_ + h) * HD_ + hd) * S_ + s] = val;
        }
      }
    }
}

// ---------------- fused RMSNorm + RoPE (in place), (b, s, h) block order ----------------
template<int LOGNH>
__global__ __launch_bounds__(256) void normrope_kernel(bf16_t* __restrict__ x,
                                                       const float* __restrict__ w,
                                                       const float* __restrict__ cosb,
                                                       const float* __restrict__ sinb,
                                                       float* __restrict__ knorm) {
  const int gid  = blockIdx.x * 4 + (threadIdx.x >> 6);  // (b, s, h) order: h innermost
  const int lane = threadIdx.x & 63;
  const int nh = 1 << LOGNH;
  const int h  = gid & (nh - 1);
  const int bs = gid >> LOGNH;                 // b*S + s
  const int b  = bs >> 11, s = bs & (S_ - 1);
  const int rowi = (b * nh + h) * S_ + s;

  bf16_t* ptr = x + (size_t)rowi * HD_ + lane * 4;
  bf16x4 xv = *(const bf16x4*)ptr;
  float v0 = (float)xv[0], v1 = (float)xv[1], v2 = (float)xv[2], v3 = (float)xv[3];
  float ss = v0 * v0 + v1 * v1 + v2 * v2 + v3 * v3;
#pragma unroll
  for (int off = 1; off < 64; off <<= 1) ss += __shfl_xor(ss, off);
  float r = rsqrtf(ss * (1.0f / HD_) + 1e-6f);

  float4 wv = *(const float4*)(w + lane * 4);
  float x0 = v0 * r * (1.0f + wv.x);
  float x1 = v1 * r * (1.0f + wv.y);
  float x2 = v2 * r * (1.0f + wv.z);
  float x3 = v3 * r * (1.0f + wv.w);

  if (knorm != nullptr) {   // row norm^2 (RoPE rotates pairs: norm preserved)
    float s2 = x0 * x0 + x1 * x1 + x2 * x2 + x3 * x3;
#pragma unroll
    for (int off = 1; off < 64; off <<= 1) s2 += __shfl_xor(s2, off);
    if (lane == 0) knorm[rowi] = s2;
  }

  float p0 = __shfl_xor(x0, 32);
  float p1 = __shfl_xor(x1, 32);
  float p2 = __shfl_xor(x2, 32);
  float p3 = __shfl_xor(x3, 32);
  float sgn = (lane < 32) ? -1.0f : 1.0f;

  float4 c  = *(const float4*)(cosb + (size_t)bs * HD_ + lane * 4);
  float4 sn = *(const float4*)(sinb + (size_t)bs * HD_ + lane * 4);
  bf16x4 o;
  o[0] = (bf16_t)(x0 * c.x + sgn * p0 * sn.x);
  o[1] = (bf16_t)(x1 * c.y + sgn * p1 * sn.y);
  o[2] = (bf16_t)(x2 * c.z + sgn * p2 * sn.z);
  o[3] = (bf16_t)(x3 * c.w + sgn * p3 * sn.w);
  *(bf16x4*)ptr = o;
}

// ---------------- per-(b,kv-head) max of knorm ----------------
__global__ __launch_bounds__(256) void kmax_reduce_kernel(const float* __restrict__ knorm,
                                                          float* __restrict__ km) {
  __shared__ float red[4];
  const int t = threadIdx.x;
  const float* src = knorm + (size_t)blockIdx.x * S_;
  float m = 0.0f;
  for (int i = t; i < S_; i += 256) m = fmaxf(m, src[i]);
#pragma unroll
  for (int off = 1; off < 64; off <<= 1) m = fmaxf(m, __shfl_xor(m, off));
  if ((t & 63) == 0) red[t >> 6] = m;
  __syncthreads();
  if (t == 0) km[blockIdx.x] = fmaxf(fmaxf(red[0], red[1]), fmaxf(red[2], red[3]));
}

// ---------------- weights upper-region zeros: cols >= (row & ~31) + 32 ----------------
__global__ __launch_bounds__(256) void wzero_kernel(float* __restrict__ wbuf) {
  const int wv = threadIdx.x >> 6, lane = threadIdx.x & 63;
  const size_t rg = (size_t)blockIdx.x * 4 + wv;     // row in (B*NH, S)
  const int row = (int)(rg & (S_ - 1));
  const int start = (row & ~31) + 32;
  float* base = wbuf + rg * S_;
  const float4 z = make_float4(0.f, 0.f, 0.f, 0.f);
  for (int c = start + lane * 4; c < S_; c += 256) *(float4*)(base + c) = z;
}

// ---------------- single-pass flash attention + fused weight normalization ----------------
// Writes p-tilde to wout during the loop, then each wave rescales its own rows in place
// (cols < (row&~31)+32; wzero covers the rest). T14 prefetch: next tile loads issue
// before current tile's compute.
__global__ __launch_bounds__(256) void attn1p_kernel(const bf16_t* __restrict__ qb,
                                                     const bf16_t* __restrict__ kb,
                                                     const bf16_t* __restrict__ vt,
                                                     const float* __restrict__ kmaxbuf,
                                                     float* __restrict__ wout,
                                                     bf16_t* __restrict__ ctx) {
  __shared__ __align__(16) bf16_t Ks[32][264];      // +8 pad
  __shared__ __align__(16) bf16_t Vs[256][40];      // d-major, +8 pad
  __shared__ __align__(16) bf16_t p_lds[4][16][40];
  __shared__ float qn_lds[4][16];
  __shared__ float il_lds[4][16];

  const int t = threadIdx.x, w = t >> 6, lane = t & 63;
  const int lr = lane & 15, lg = lane >> 4, rloc = lg * 4;
  const int q0b = blockIdx.x * 64;
  const int q0  = q0b + w * 16;
  const int bh = blockIdx.y, b = bh >> 4, h = bh & 15, kvh = h >> 1;

  const bf16_t* qptr = qb + ((size_t)(b * NH_ + h) * S_ + q0 + lr) * HD_ + lg * 8;
  bf16x8 qf[8];
#pragma unroll
  for (int c = 0; c < 8; ++c) qf[c] = *(const bf16x8*)(qptr + c * 32);

  float qn = 0.0f;
#pragma unroll
  for (int c = 0; c < 8; ++c)
#pragma unroll
    for (int e = 0; e < 8; ++e) { float v = (float)qf[c][e]; qn += v * v; }
  qn += __shfl_xor(qn, 16);
  qn += __shfl_xor(qn, 32);
  if (lg == 0) qn_lds[w][lr] = qn;
  __syncthreads();
  const float kmax2 = kmaxbuf[b * NKV_ + kvh];
  float mb[4];
#pragma unroll
  for (int r = 0; r < 4; ++r)
    mb[r] = SCALE_ * sqrtf(qn_lds[w][rloc + r] * kmax2) + 1.0f;  // >= any score, with margin

  float l[4] = {0.f, 0.f, 0.f, 0.f};
  f32x4 oacc[16] = {};
  const int nkt = (q0b + 64) >> 5;
  float* wrow = wout + ((size_t)bh * S_ + q0) * S_;
  const bf16_t* kgb = kb + (size_t)(b * NKV_ + kvh) * S_ * HD_;
  const bf16_t* vgb = vt + (size_t)(b * NKV_ + kvh) * HD_ * S_;

  const int s_st = t >> 3, c_st = (t & 7) * 32;   // K staging: row s_st, 32 cols
  const int vd   = t >> 3, vc   = (t & 7) * 4;    // V staging: rows vd+32i, 4 cols

  // ---- prefetch tile 0 into registers ----
  bf16x8 kreg0, kreg1, kreg2, kreg3;
  bf16x4 vreg[8];
  {
    const bf16_t* src = kgb + (size_t)s_st * HD_ + c_st;
    kreg0 = *(const bf16x8*)(src);
    kreg1 = *(const bf16x8*)(src + 8);
    kreg2 = *(const bf16x8*)(src + 16);
    kreg3 = *(const bf16x8*)(src + 24);
#pragma unroll
    for (int i = 0; i < 8; ++i)
      vreg[i] = *(const bf16x4*)(vgb + (size_t)(vd + i * 32) * S_ + vc);
  }

  for (int kt = 0; kt < nkt; ++kt) {
    const int colb = kt * 32;
    __syncthreads();   // previous tile's LDS reads complete
    *(bf16x8*)&Ks[s_st][c_st]      = kreg0;
    *(bf16x8*)&Ks[s_st][c_st + 8]  = kreg1;
    *(bf16x8*)&Ks[s_st][c_st + 16] = kreg2;
    *(bf16x8*)&Ks[s_st][c_st + 24] = kreg3;
#pragma unroll
    for (int i = 0; i < 8; ++i) *(bf16x4*)&Vs[vd + i * 32][vc] = vreg[i];
    __syncthreads();

    if (kt + 1 < nkt) {   // T14: issue next tile's loads; latency hides under compute
      const int nb = colb + 32;
      const bf16_t* src = kgb + (size_t)(nb + s_st) * HD_ + c_st;
      kreg0 = *(const bf16x8*)(src);
      kreg1 = *(const bf16x8*)(src + 8);
      kreg2 = *(const bf16x8*)(src + 16);
      kreg3 = *(const bf16x8*)(src + 24);
#pragma unroll
      for (int i = 0; i < 8; ++i)
        vreg[i] = *(const bf16x4*)(vgb + (size_t)(vd + i * 32) * S_ + nb + vc);
    }

    if (colb <= q0 + 15) {   // wave active for this tile
      f32x4 s0 = {0.f, 0.f, 0.f, 0.f}, s1 = {0.f, 0.f, 0.f, 0.f};
#pragma unroll
      for (int c = 0; c < 8; ++c) {
        bf16x8 k0 = *(const bf16x8*)&Ks[lr][c * 32 + lg * 8];
        bf16x8 k1 = *(const bf16x8*)&Ks[16 + lr][c * 32 + lg * 8];
        s0 = __builtin_amdgcn_mfma_f32_16x16x32_bf16(qf[c], k0, s0, 0, 0, 0);
        s1 = __builtin_amdgcn_mfma_f32_16x16x32_bf16(qf[c], k1, s1, 0, 0, 0);
      }
      const int col0 = colb + lr, col1 = col0 + 16;
#pragma unroll
      for (int r = 0; r < 4; ++r) {
        const int row = q0 + rloc + r;
        const float pa = (col0 <= row) ? __expf(s0[r] * SCALE_ - mb[r]) : 0.0f;
        const float pb = (col1 <= row) ? __expf(s1[r] * SCALE_ - mb[r]) : 0.0f;
        l[r] += pa + pb;
        wrow[(size_t)(rloc + r) * S_ + col0] = pa;
        wrow[(size_t)(rloc + r) * S_ + col1] = pb;
        p_lds[w][rloc + r][lr]      = (bf16_t)pa;
        p_lds[w][rloc + r][lr + 16] = (bf16_t)pb;
      }
      bf16x8 pf = *(const bf16x8*)&p_lds[w][lr][lg * 8];   // P as A-fragment
#pragma unroll
      for (int df = 0; df < 16; ++df) {
        bf16x8 vf = *(const bf16x8*)&Vs[df * 16 + lr][lg * 8];
        oacc[df] = __builtin_amdgcn_mfma_f32_16x16x32_bf16(pf, vf, oacc[df], 0, 0, 0);
      }
    }
  }
  // row sum l across lr lanes
#pragma unroll
  for (int r = 0; r < 4; ++r) {
    l[r] += __shfl_xor(l[r], 1);
    l[r] += __shfl_xor(l[r], 2);
    l[r] += __shfl_xor(l[r], 4);
    l[r] += __shfl_xor(l[r], 8);
  }
  float invl[4];
#pragma unroll
  for (int r = 0; r < 4; ++r) invl[r] = 1.0f / l[r];
  if (lr == 0) {
#pragma unroll
    for (int r = 0; r < 4; ++r) il_lds[w][rloc + r] = invl[r];
  }

  // ctx epilogue
  bf16_t* cp = ctx + ((size_t)b * S_ + q0) * DQ_ + h * HD_;
#pragma unroll
  for (int df = 0; df < 16; ++df)
#pragma unroll
    for (int r = 0; r < 4; ++r)
      cp[(size_t)(rloc + r) * DQ_ + df * 16 + lr] = (bf16_t)(oacc[df][r] * invl[r]);

  // fused weight normalization: wave rescales its own 16 rows (stores are its own;
  // vmcnt(0) ensures they reached L2; L1 is write-through/invalidate on CDNA)
  asm volatile("s_waitcnt vmcnt(0)" ::: "memory");
#pragma unroll 1
  for (int r16 = 0; r16 < 16; ++r16) {
    const int row = q0 + r16;
    const int bnd = (row & ~31) + 32;          // written-col extent for this row
    const float inv = il_lds[w][r16];
    float* rp = wrow + (size_t)r16 * S_;
    for (int c = lane * 4; c < bnd; c += 256) {
      float4 v = *(const float4*)(rp + c);
      v.x *= inv; v.y *= inv; v.z *= inv; v.w *= inv;
      *(float4*)(rp + c) = v;
    }
  }
}

// ---------------- launch ----------------
extern "C" void kernel_launch(void* const* d_in, const int* in_sizes, int n_in,
                              void* d_out, int out_size, void* d_ws, size_t ws_size,
                              hipStream_t stream) {
  const float* hs   = (const float*)d_in[0];
  const float* cosb = (const float*)d_in[1];
  const float* sinb = (const float*)d_in[2];
  // d_in[3] attention_mask: recomputed causally in-kernel
  const float* Wq = (const float*)d_in[4];
  const float* Wk = (const float*)d_in[5];
  const float* Wv = (const float*)d_in[6];
  const float* Wo = (const float*)d_in[7];
  const float* qw = (const float*)d_in[8];
  const float* kw = (const float*)d_in[9];

  char* ws = (char*)d_ws;
  bf16_t* qb    = (bf16_t*)(ws + 0);            // 33,554,432  (B,NH,S,HD)
  bf16_t* kb    = (bf16_t*)(ws + 33554432);     // 16,777,216  (B,NKV,S,HD)
  bf16_t* vt    = (bf16_t*)(ws + 50331648);     // 16,777,216  (B,NKV,HD,S)
  bf16_t* ctx   = (bf16_t*)(ws + 67108864);     // 33,554,432  (B,S,NH*HD)
  float*  knorm = (float*)(ws + 100925440);     //    131,072
  float*  km    = (float*)(ws + 101056512);     //        128
  bf16_t* hsb   = (bf16_t*)(ws + 101056640);    // 29,360,128  (B*S, HID) bf16
  bf16_t* wqb   = (bf16_t*)(ws + 130416768);    // 29,360,128
  bf16_t* wkb   = (bf16_t*)(ws + 159776896);    // 14,680,064
  bf16_t* wvb   = (bf16_t*)(ws + 174456960);    // 14,680,064
  bf16_t* wob   = (bf16_t*)(ws + 189137024);    // 29,360,128  -> total 218,497,152

  float* out      = (float*)d_out;
  float* attn_out = out;                            // (B,S,HID) f32
  float* weights  = out + (size_t)B_ * S_ * HID_;   // (B,NH,S,S) f32

  const int M = B_ * S_;  // 4096

  // 0) one-shot bf16 conversion of activations + weights
  cvt_kernel<<<14336, 256, 0, stream>>>(hs, hsb, (B_ * S_ * HID_) / 4);
  cvt_kernel<<<14336, 256, 0, stream>>>(Wq, wqb, (DQ_ * HID_) / 4);
  cvt_kernel<<<7168,  256, 0, stream>>>(Wk, wkb, (DKV_ * HID_) / 4);
  cvt_kernel<<<7168,  256, 0, stream>>>(Wv, wvb, (DKV_ * HID_) / 4);
  cvt_kernel<<<14336, 256, 0, stream>>>(Wo, wob, (HID_ * DQ_) / 4);

  // 1) projections (bf16 x bf16, global_load_lds staging)
  gemm_lds<1><<<dim3(DQ_ / 128, M / 128), 256, 0, stream>>>(hsb, wqb, qb, M, DQ_, HID_, NH_);
  gemm_lds<1><<<dim3(DKV_ / 128, M / 128), 256, 0, stream>>>(hsb, wkb, kb, M, DKV_, HID_, NKV_);
  gemm_lds<2><<<dim3(DKV_ / 128, M / 128), 256, 0, stream>>>(hsb, wvb, vt, M, DKV_, HID_, NKV_);

  // 2) norm + rope (in place); K pass also stores per-row |k|^2
  normrope_kernel<4><<<(B_ * S_ * NH_) / 4, 256, 0, stream>>>(qb, qw, cosb, sinb, nullptr);
  normrope_kernel<3><<<(B_ * S_ * NKV_) / 4, 256, 0, stream>>>(kb, kw, cosb, sinb, knorm);
  kmax_reduce_kernel<<<B_ * NKV_, 256, 0, stream>>>(knorm, km);

  // 3) zero the never-written upper region of weights (store-only)
  wzero_kernel<<<(B_ * NH_ * S_) / 4, 256, 0, stream>>>(weights);

  // 4) single-pass attention with fused weight normalization
  attn1p_kernel<<<dim3(S_ / 64, B_ * NH_), 256, 0, stream>>>(qb, kb, vt, km, weights, ctx);

  // 5) output projection -> d_out (f32)
  gemm_lds<0><<<dim3(HID_ / 128, M / 128), 256, 0, stream>>>(ctx, wob, attn_out, M, HID_, DQ_, 0);
}

// Round 10
// 1282.797 us; speedup vs baseline: 1.0394x; 1.0394x over previous
//
#include <hip/hip_runtime.h>

// ---------------- problem constants ----------------
#define B_    2
#define S_    2048
#define HID_  3584
#define NH_   16
#define NKV_  8
#define HD_   256
#define DQ_   (NH_ * HD_)    // 4096
#define DKV_  (NKV_ * HD_)   // 2048

static constexpr float SCALE_ = 0.0625f;   // 256^-0.5

typedef __bf16 bf16_t;
typedef __bf16 bf16x8 __attribute__((ext_vector_type(8)));
typedef __bf16 bf16x4 __attribute__((ext_vector_type(4)));
typedef float  f32x4  __attribute__((ext_vector_type(4)));

// ---------------- f32 -> bf16 convert ----------------
__global__ __launch_bounds__(256) void cvt_kernel(const float* __restrict__ in,
                                                  bf16_t* __restrict__ out, int n4) {
  int i = blockIdx.x * 256 + threadIdx.x;
  if (i < n4) {
    float4 v = ((const float4*)in)[i];
    bf16x4 o;
    o[0] = (bf16_t)v.x; o[1] = (bf16_t)v.y; o[2] = (bf16_t)v.z; o[3] = (bf16_t)v.w;
    ((bf16x4*)out)[i] = o;
  }
}

// ---------------- async global->LDS, 16B per lane ----------------
__device__ inline void gload_lds16(const bf16_t* g, bf16_t* l) {
  __builtin_amdgcn_global_load_lds(
      (const __attribute__((address_space(1))) void*)g,
      (__attribute__((address_space(3))) void*)l, 16, 0, 0);
}

// ---------------- GEMM (m97 structure): C[m][n] = sum_k A[m][k]*Bt[n][k], both bf16 ----------------
// MODE 0: OUT f32, plain row-major [M][N]          (o-proj -> d_out)
// MODE 1: OUT bf16, relayout to (B, nh, S, HD)     (Q, K projections)
// MODE 2: OUT bf16, transpose to (B, NKV, HD, S)   (V projection)
template<int MODE>
__global__ __launch_bounds__(256) void gemm_lds(const bf16_t* __restrict__ A,
                                                const bf16_t* __restrict__ Bt,
                                                void* __restrict__ outv,
                                                int M, int N, int K, int nh) {
  __shared__ __align__(16) bf16_t As[128 * 32];
  __shared__ __align__(16) bf16_t Bs[128 * 32];
  const int t = threadIdx.x;
  const int lane = t & 63, wv = t >> 6;
  const int wr = wv >> 1, wc = wv & 1;
  const int lr = lane & 15, lg = lane >> 4;
  const size_t m0 = (size_t)blockIdx.y * 128, n0 = (size_t)blockIdx.x * 128;

  const int srow = wv * 32 + (lane >> 2);
  const int scol = (lane & 3) * 8;
  const bf16_t* ga0 = A  + (m0 + srow) * (size_t)K + scol;
  const bf16_t* gb0 = Bt + (n0 + srow) * (size_t)K + scol;
  bf16_t* la0 = &As[wv * 1024];        // wave-uniform LDS bases
  bf16_t* la1 = &As[wv * 1024 + 512];
  bf16_t* lb0 = &Bs[wv * 1024];
  bf16_t* lb1 = &Bs[wv * 1024 + 512];
  const size_t k16 = 16 * (size_t)K;

  f32x4 acc[4][4] = {};
  for (int k0 = 0; k0 < K; k0 += 32) {
    __syncthreads();
    gload_lds16(ga0 + k0,       la0);
    gload_lds16(ga0 + k16 + k0, la1);
    gload_lds16(gb0 + k0,       lb0);
    gload_lds16(gb0 + k16 + k0, lb1);
    __syncthreads();

    bf16x8 af[4], bfr[4];
#pragma unroll
    for (int i = 0; i < 4; ++i) af[i]  = *(const bf16x8*)&As[(wr * 64 + i * 16 + lr) * 32 + lg * 8];
#pragma unroll
    for (int j = 0; j < 4; ++j) bfr[j] = *(const bf16x8*)&Bs[(wc * 64 + j * 16 + lr) * 32 + lg * 8];
#pragma unroll
    for (int i = 0; i < 4; ++i)
#pragma unroll
      for (int j = 0; j < 4; ++j)
        acc[i][j] = __builtin_amdgcn_mfma_f32_16x16x32_bf16(af[i], bfr[j], acc[i][j], 0, 0, 0);
  }
#pragma unroll
  for (int i = 0; i < 4; ++i)
#pragma unroll
    for (int j = 0; j < 4; ++j) {
      const int row0 = (int)m0 + wr * 64 + i * 16 + lg * 4;
      const int col  = (int)n0 + wc * 64 + j * 16 + lr;
#pragma unroll
      for (int r = 0; r < 4; ++r) {
        const int row = row0 + r;
        if (MODE == 0) {
          ((float*)outv)[(size_t)row * N + col] = acc[i][j][r];
        } else {
          bf16_t* out = (bf16_t*)outv;
          const bf16_t val = (bf16_t)acc[i][j][r];
          const int b = row >> 11, s = row & (S_ - 1);
          const int h = col >> 8,  hd = col & (HD_ - 1);
          if (MODE == 1) out[((size_t)(b * nh + h) * S_ + s) * HD_ + hd] = val;
          else           out[((size_t)(b * NKV_ + h) * HD_ + hd) * S_ + s] = val;
        }
      }
    }
}

// ---------------- fused RMSNorm + RoPE (in place), (b, s, h) block order ----------------
template<int LOGNH>
__global__ __launch_bounds__(256) void normrope_kernel(bf16_t* __restrict__ x,
                                                       const float* __restrict__ w,
                                                       const float* __restrict__ cosb,
                                                       const float* __restrict__ sinb,
                                                       float* __restrict__ knorm) {
  const int gid  = blockIdx.x * 4 + (threadIdx.x >> 6);  // (b, s, h) order: h innermost
  const int lane = threadIdx.x & 63;
  const int nh = 1 << LOGNH;
  const int h  = gid & (nh - 1);
  const int bs = gid >> LOGNH;                 // b*S + s
  const int b  = bs >> 11, s = bs & (S_ - 1);
  const int rowi = (b * nh + h) * S_ + s;

  bf16_t* ptr = x + (size_t)rowi * HD_ + lane * 4;
  bf16x4 xv = *(const bf16x4*)ptr;
  float v0 = (float)xv[0], v1 = (float)xv[1], v2 = (float)xv[2], v3 = (float)xv[3];
  float ss = v0 * v0 + v1 * v1 + v2 * v2 + v3 * v3;
#pragma unroll
  for (int off = 1; off < 64; off <<= 1) ss += __shfl_xor(ss, off);
  float r = rsqrtf(ss * (1.0f / HD_) + 1e-6f);

  float4 wv = *(const float4*)(w + lane * 4);
  float x0 = v0 * r * (1.0f + wv.x);
  float x1 = v1 * r * (1.0f + wv.y);
  float x2 = v2 * r * (1.0f + wv.z);
  float x3 = v3 * r * (1.0f + wv.w);

  if (knorm != nullptr) {   // row norm^2 (RoPE rotates pairs: norm preserved)
    float s2 = x0 * x0 + x1 * x1 + x2 * x2 + x3 * x3;
#pragma unroll
    for (int off = 1; off < 64; off <<= 1) s2 += __shfl_xor(s2, off);
    if (lane == 0) knorm[rowi] = s2;
  }

  float p0 = __shfl_xor(x0, 32);
  float p1 = __shfl_xor(x1, 32);
  float p2 = __shfl_xor(x2, 32);
  float p3 = __shfl_xor(x3, 32);
  float sgn = (lane < 32) ? -1.0f : 1.0f;

  float4 c  = *(const float4*)(cosb + (size_t)bs * HD_ + lane * 4);
  float4 sn = *(const float4*)(sinb + (size_t)bs * HD_ + lane * 4);
  bf16x4 o;
  o[0] = (bf16_t)(x0 * c.x + sgn * p0 * sn.x);
  o[1] = (bf16_t)(x1 * c.y + sgn * p1 * sn.y);
  o[2] = (bf16_t)(x2 * c.z + sgn * p2 * sn.z);
  o[3] = (bf16_t)(x3 * c.w + sgn * p3 * sn.w);
  *(bf16x4*)ptr = o;
}

// ---------------- per-(b,kv-head) max of knorm ----------------
__global__ __launch_bounds__(256) void kmax_reduce_kernel(const float* __restrict__ knorm,
                                                          float* __restrict__ km) {
  __shared__ float red[4];
  const int t = threadIdx.x;
  const float* src = knorm + (size_t)blockIdx.x * S_;
  float m = 0.0f;
  for (int i = t; i < S_; i += 256) m = fmaxf(m, src[i]);
#pragma unroll
  for (int off = 1; off < 64; off <<= 1) m = fmaxf(m, __shfl_xor(m, off));
  if ((t & 63) == 0) red[t >> 6] = m;
  __syncthreads();
  if (t == 0) km[blockIdx.x] = fmaxf(fmaxf(red[0], red[1]), fmaxf(red[2], red[3]));
}

// ---------------- single-pass flash attention, 4 waves x 16 q-rows, bound-based softmax ----------------
// LDS trimmed to 40,192 B -> 4 blocks/CU; LPT block order (longest first); 16B/lane V staging.
__global__ __launch_bounds__(256, 4) void attn1p_kernel(const bf16_t* __restrict__ qb,
                                                        const bf16_t* __restrict__ kb,
                                                        const bf16_t* __restrict__ vt,
                                                        const float* __restrict__ kmaxbuf,
                                                        float* __restrict__ wout,
                                                        float* __restrict__ linv,
                                                        bf16_t* __restrict__ ctx) {
  __shared__ __align__(16) bf16_t Ks[32][264];      // +8 pad
  __shared__ __align__(16) bf16_t Vs[256][36];      // d-major, +4 pad (18-dword stride)
  __shared__ __align__(16) bf16_t p_lds[4][16][36];
  __shared__ float qn_lds[4][16];

  const int t = threadIdx.x, w = t >> 6, lane = t & 63;
  const int lr = lane & 15, lg = lane >> 4, rloc = lg * 4;
  const int qbucket = gridDim.x - 1 - blockIdx.x;   // LPT: longest blocks dispatch first
  const int q0b = qbucket * 64;
  const int q0  = q0b + w * 16;
  const int bh = blockIdx.y, b = bh >> 4, h = bh & 15, kvh = h >> 1;

  const bf16_t* qptr = qb + ((size_t)(b * NH_ + h) * S_ + q0 + lr) * HD_ + lg * 8;
  bf16x8 qf[8];
#pragma unroll
  for (int c = 0; c < 8; ++c) qf[c] = *(const bf16x8*)(qptr + c * 32);

  float qn = 0.0f;
#pragma unroll
  for (int c = 0; c < 8; ++c)
#pragma unroll
    for (int e = 0; e < 8; ++e) { float v = (float)qf[c][e]; qn += v * v; }
  qn += __shfl_xor(qn, 16);
  qn += __shfl_xor(qn, 32);
  if (lg == 0) qn_lds[w][lr] = qn;
  __syncthreads();
  const float kmax2 = kmaxbuf[b * NKV_ + kvh];
  float mb[4];
#pragma unroll
  for (int r = 0; r < 4; ++r)
    mb[r] = SCALE_ * sqrtf(qn_lds[w][rloc + r] * kmax2) + 1.0f;  // >= any score, with margin

  float l[4] = {0.f, 0.f, 0.f, 0.f};
  f32x4 oacc[16] = {};
  const int nkt = (q0b + 64) >> 5;
  float* wrow = wout + ((size_t)bh * S_ + q0) * S_;
  const bf16_t* kgb = kb + (size_t)(b * NKV_ + kvh) * S_ * HD_;
  const bf16_t* vgb = vt + (size_t)(b * NKV_ + kvh) * HD_ * S_;

  const int s_st = t >> 3, c_st = (t & 7) * 32;   // K staging: row s_st, 4x8 cols
  const int vrow = t >> 2, vcol = (t & 3) * 8;    // V staging: rows vrow+64i, 8 cols (16B)

  for (int kt = 0; kt < nkt; ++kt) {
    const int colb = kt * 32;
    __syncthreads();   // previous tile's LDS reads complete
    {  // stage K tile (32 x 256) coalesced
      const bf16_t* src = kgb + (size_t)(colb + s_st) * HD_ + c_st;
      bf16x8 k0 = *(const bf16x8*)(src);
      bf16x8 k1 = *(const bf16x8*)(src + 8);
      bf16x8 k2 = *(const bf16x8*)(src + 16);
      bf16x8 k3 = *(const bf16x8*)(src + 24);
      *(bf16x8*)&Ks[s_st][c_st]      = k0;
      *(bf16x8*)&Ks[s_st][c_st + 8]  = k1;
      *(bf16x8*)&Ks[s_st][c_st + 16] = k2;
      *(bf16x8*)&Ks[s_st][c_st + 24] = k3;
    }
#pragma unroll
    for (int i = 0; i < 4; ++i) {  // stage V tile (256 d x 32 s), 16B per lane per pass
      const int d = vrow + i * 64;
      bf16x8 vv = *(const bf16x8*)(vgb + (size_t)d * S_ + colb + vcol);
      *(bf16x8*)&Vs[d][vcol] = vv;
    }
    __syncthreads();

    if (colb <= q0 + 15) {   // wave active for this tile
      f32x4 s0 = {0.f, 0.f, 0.f, 0.f}, s1 = {0.f, 0.f, 0.f, 0.f};
#pragma unroll
      for (int c = 0; c < 8; ++c) {
        bf16x8 k0 = *(const bf16x8*)&Ks[lr][c * 32 + lg * 8];
        bf16x8 k1 = *(const bf16x8*)&Ks[16 + lr][c * 32 + lg * 8];
        s0 = __builtin_amdgcn_mfma_f32_16x16x32_bf16(qf[c], k0, s0, 0, 0, 0);
        s1 = __builtin_amdgcn_mfma_f32_16x16x32_bf16(qf[c], k1, s1, 0, 0, 0);
      }
      const int col0 = colb + lr, col1 = col0 + 16;
#pragma unroll
      for (int r = 0; r < 4; ++r) {
        const int row = q0 + rloc + r;
        const float pa = (col0 <= row) ? __expf(s0[r] * SCALE_ - mb[r]) : 0.0f;
        const float pb = (col1 <= row) ? __expf(s1[r] * SCALE_ - mb[r]) : 0.0f;
        l[r] += pa + pb;
        wrow[(size_t)(rloc + r) * S_ + col0] = pa;
        wrow[(size_t)(rloc + r) * S_ + col1] = pb;
        p_lds[w][rloc + r][lr]      = (bf16_t)pa;
        p_lds[w][rloc + r][lr + 16] = (bf16_t)pb;
      }
      bf16x8 pf = *(const bf16x8*)&p_lds[w][lr][lg * 8];   // P as A-fragment
#pragma unroll
      for (int df = 0; df < 16; ++df) {
        bf16x8 vf = *(const bf16x8*)&Vs[df * 16 + lr][lg * 8];
        oacc[df] = __builtin_amdgcn_mfma_f32_16x16x32_bf16(pf, vf, oacc[df], 0, 0, 0);
      }
    }
  }
  // row sum l across lr lanes
#pragma unroll
  for (int r = 0; r < 4; ++r) {
    l[r] += __shfl_xor(l[r], 1);
    l[r] += __shfl_xor(l[r], 2);
    l[r] += __shfl_xor(l[r], 4);
    l[r] += __shfl_xor(l[r], 8);
  }
  float invl[4];
#pragma unroll
  for (int r = 0; r < 4; ++r) invl[r] = 1.0f / l[r];

  bf16_t* cp = ctx + ((size_t)b * S_ + q0) * DQ_ + h * HD_;
#pragma unroll
  for (int df = 0; df < 16; ++df)
#pragma unroll
    for (int r = 0; r < 4; ++r)
      cp[(size_t)(rloc + r) * DQ_ + df * 16 + lr] = (bf16_t)(oacc[df][r] * invl[r]);

  if (lr == 0) {
#pragma unroll
    for (int r = 0; r < 4; ++r) linv[(size_t)bh * S_ + q0 + rloc + r] = invl[r];
  }
}

// ---------------- weights post-pass: scale lower triangle by 1/l, zero upper ----------------
__global__ __launch_bounds__(256) void wscale_kernel(float* __restrict__ wbuf,
                                                     const float* __restrict__ linv) {
  const int wv = threadIdx.x >> 6, lane = threadIdx.x & 63;
  const size_t rg = (size_t)blockIdx.x * 4 + wv;     // global row in (B*NH, S)
  const int row = (int)(rg & (S_ - 1));
  const float inv = linv[rg];
  float* base = wbuf + rg * S_;
#pragma unroll
  for (int i = 0; i < 8; ++i) {
    const int c0 = (i * 64 + lane) * 4;
    float4 v;
    if (c0 > row) {
      v = make_float4(0.f, 0.f, 0.f, 0.f);
    } else {
      v = *(const float4*)(base + c0);
      v.x = (c0 + 0 <= row) ? v.x * inv : 0.f;
      v.y = (c0 + 1 <= row) ? v.y * inv : 0.f;
      v.z = (c0 + 2 <= row) ? v.z * inv : 0.f;
      v.w = (c0 + 3 <= row) ? v.w * inv : 0.f;
    }
    *(float4*)(base + c0) = v;
  }
}

// ---------------- launch ----------------
extern "C" void kernel_launch(void* const* d_in, const int* in_sizes, int n_in,
                              void* d_out, int out_size, void* d_ws, size_t ws_size,
                              hipStream_t stream) {
  const float* hs   = (const float*)d_in[0];
  const float* cosb = (const float*)d_in[1];
  const float* sinb = (const float*)d_in[2];
  // d_in[3] attention_mask: recomputed causally in-kernel
  const float* Wq = (const float*)d_in[4];
  const float* Wk = (const float*)d_in[5];
  const float* Wv = (const float*)d_in[6];
  const float* Wo = (const float*)d_in[7];
  const float* qw = (const float*)d_in[8];
  const float* kw = (const float*)d_in[9];

  char* ws = (char*)d_ws;
  bf16_t* qb    = (bf16_t*)(ws + 0);            // 33,554,432  (B,NH,S,HD)
  bf16_t* kb    = (bf16_t*)(ws + 33554432);     // 16,777,216  (B,NKV,S,HD)
  bf16_t* vt    = (bf16_t*)(ws + 50331648);     // 16,777,216  (B,NKV,HD,S)
  bf16_t* ctx   = (bf16_t*)(ws + 67108864);     // 33,554,432  (B,S,NH*HD)
  float*  linv  = (float*)(ws + 100663296);     //    262,144
  float*  knorm = (float*)(ws + 100925440);     //    131,072
  float*  km    = (float*)(ws + 101056512);     //        128
  bf16_t* hsb   = (bf16_t*)(ws + 101056640);    // 29,360,128  (B*S, HID) bf16
  bf16_t* wqb   = (bf16_t*)(ws + 130416768);    // 29,360,128
  bf16_t* wkb   = (bf16_t*)(ws + 159776896);    // 14,680,064
  bf16_t* wvb   = (bf16_t*)(ws + 174456960);    // 14,680,064
  bf16_t* wob   = (bf16_t*)(ws + 189137024);    // 29,360,128  -> total 218,497,152

  float* out      = (float*)d_out;
  float* attn_out = out;                            // (B,S,HID) f32
  float* weights  = out + (size_t)B_ * S_ * HID_;   // (B,NH,S,S) f32

  const int M = B_ * S_;  // 4096

  // 0) one-shot bf16 conversion of activations + weights
  cvt_kernel<<<14336, 256, 0, stream>>>(hs, hsb, (B_ * S_ * HID_) / 4);
  cvt_kernel<<<14336, 256, 0, stream>>>(Wq, wqb, (DQ_ * HID_) / 4);
  cvt_kernel<<<7168,  256, 0, stream>>>(Wk, wkb, (DKV_ * HID_) / 4);
  cvt_kernel<<<7168,  256, 0, stream>>>(Wv, wvb, (DKV_ * HID_) / 4);
  cvt_kernel<<<14336, 256, 0, stream>>>(Wo, wob, (HID_ * DQ_) / 4);

  // 1) projections (bf16 x bf16, global_load_lds staging)
  gemm_lds<1><<<dim3(DQ_ / 128, M / 128), 256, 0, stream>>>(hsb, wqb, qb, M, DQ_, HID_, NH_);
  gemm_lds<1><<<dim3(DKV_ / 128, M / 128), 256, 0, stream>>>(hsb, wkb, kb, M, DKV_, HID_, NKV_);
  gemm_lds<2><<<dim3(DKV_ / 128, M / 128), 256, 0, stream>>>(hsb, wvb, vt, M, DKV_, HID_, NKV_);

  // 2) norm + rope (in place); K pass also stores per-row |k|^2
  normrope_kernel<4><<<(B_ * S_ * NH_) / 4, 256, 0, stream>>>(qb, qw, cosb, sinb, nullptr);
  normrope_kernel<3><<<(B_ * S_ * NKV_) / 4, 256, 0, stream>>>(kb, kw, cosb, sinb, knorm);
  kmax_reduce_kernel<<<B_ * NKV_, 256, 0, stream>>>(knorm, km);

  // 3) single-pass attention (unnormalized p-tilde into weights buffer)
  attn1p_kernel<<<dim3(S_ / 64, B_ * NH_), 256, 0, stream>>>(qb, kb, vt, km, weights, linv, ctx);

  // 4) weights normalization + upper-triangle zeros
  wscale_kernel<<<(B_ * NH_ * S_) / 4, 256, 0, stream>>>(weights, linv);

  // 5) output projection -> d_out (f32)
  gemm_lds<0><<<dim3(HID_ / 128, M / 128), 256, 0, stream>>>(ctx, wob, attn_out, M, HID_, DQ_, 0);
}

// Round 11
// 1261.906 us; speedup vs baseline: 1.0566x; 1.0166x over previous
//
#include <hip/hip_runtime.h>

// ---------------- problem constants ----------------
#define B_    2
#define S_    2048
#define HID_  3584
#define NH_   16
#define NKV_  8
#define HD_   256
#define DQ_   (NH_ * HD_)    // 4096
#define DKV_  (NKV_ * HD_)   // 2048

static constexpr float SCALE_ = 0.0625f;   // 256^-0.5

typedef __bf16 bf16_t;
typedef __bf16 bf16x8 __attribute__((ext_vector_type(8)));
typedef __bf16 bf16x4 __attribute__((ext_vector_type(4)));
typedef float  f32x4  __attribute__((ext_vector_type(4)));

// ---------------- f32 -> bf16 convert ----------------
__global__ __launch_bounds__(256) void cvt_kernel(const float* __restrict__ in,
                                                  bf16_t* __restrict__ out, int n4) {
  int i = blockIdx.x * 256 + threadIdx.x;
  if (i < n4) {
    float4 v = ((const float4*)in)[i];
    bf16x4 o;
    o[0] = (bf16_t)v.x; o[1] = (bf16_t)v.y; o[2] = (bf16_t)v.z; o[3] = (bf16_t)v.w;
    ((bf16x4*)out)[i] = o;
  }
}

// ---------------- async global->LDS, 16B per lane ----------------
__device__ inline void gload_lds16(const bf16_t* g, bf16_t* l) {
  __builtin_amdgcn_global_load_lds(
      (const __attribute__((address_space(1))) void*)g,
      (__attribute__((address_space(3))) void*)l, 16, 0, 0);
}

// ---------------- GEMM (m97 structure): C[m][n] = sum_k A[m][k]*Bt[n][k], both bf16 ----------------
// MODE 0: OUT f32, plain row-major [M][N]          (o-proj -> d_out)
// MODE 1: OUT bf16, relayout to (B, nh, S, HD)     (Q, K projections)
// MODE 2: OUT bf16, transpose to (B, NKV, HD, S)   (V projection)
template<int MODE>
__global__ __launch_bounds__(256) void gemm_lds(const bf16_t* __restrict__ A,
                                                const bf16_t* __restrict__ Bt,
                                                void* __restrict__ outv,
                                                int M, int N, int K, int nh) {
  __shared__ __align__(16) bf16_t As[128 * 32];
  __shared__ __align__(16) bf16_t Bs[128 * 32];
  const int t = threadIdx.x;
  const int lane = t & 63, wv = t >> 6;
  const int wr = wv >> 1, wc = wv & 1;
  const int lr = lane & 15, lg = lane >> 4;
  const size_t m0 = (size_t)blockIdx.y * 128, n0 = (size_t)blockIdx.x * 128;

  const int srow = wv * 32 + (lane >> 2);
  const int scol = (lane & 3) * 8;
  const bf16_t* ga0 = A  + (m0 + srow) * (size_t)K + scol;
  const bf16_t* gb0 = Bt + (n0 + srow) * (size_t)K + scol;
  bf16_t* la0 = &As[wv * 1024];        // wave-uniform LDS bases
  bf16_t* la1 = &As[wv * 1024 + 512];
  bf16_t* lb0 = &Bs[wv * 1024];
  bf16_t* lb1 = &Bs[wv * 1024 + 512];
  const size_t k16 = 16 * (size_t)K;

  f32x4 acc[4][4] = {};
  for (int k0 = 0; k0 < K; k0 += 32) {
    __syncthreads();
    gload_lds16(ga0 + k0,       la0);
    gload_lds16(ga0 + k16 + k0, la1);
    gload_lds16(gb0 + k0,       lb0);
    gload_lds16(gb0 + k16 + k0, lb1);
    __syncthreads();

    bf16x8 af[4], bfr[4];
#pragma unroll
    for (int i = 0; i < 4; ++i) af[i]  = *(const bf16x8*)&As[(wr * 64 + i * 16 + lr) * 32 + lg * 8];
#pragma unroll
    for (int j = 0; j < 4; ++j) bfr[j] = *(const bf16x8*)&Bs[(wc * 64 + j * 16 + lr) * 32 + lg * 8];
#pragma unroll
    for (int i = 0; i < 4; ++i)
#pragma unroll
      for (int j = 0; j < 4; ++j)
        acc[i][j] = __builtin_amdgcn_mfma_f32_16x16x32_bf16(af[i], bfr[j], acc[i][j], 0, 0, 0);
  }
#pragma unroll
  for (int i = 0; i < 4; ++i)
#pragma unroll
    for (int j = 0; j < 4; ++j) {
      const int row0 = (int)m0 + wr * 64 + i * 16 + lg * 4;
      const int col  = (int)n0 + wc * 64 + j * 16 + lr;
#pragma unroll
      for (int r = 0; r < 4; ++r) {
        const int row = row0 + r;
        if (MODE == 0) {
          ((float*)outv)[(size_t)row * N + col] = acc[i][j][r];
        } else {
          bf16_t* out = (bf16_t*)outv;
          const bf16_t val = (bf16_t)acc[i][j][r];
          const int b = row >> 11, s = row & (S_ - 1);
          const int h = col >> 8,  hd = col & (HD_ - 1);
          if (MODE == 1) out[((size_t)(b * nh + h) * S_ + s) * HD_ + hd] = val;
          else           out[((size_t)(b * NKV_ + h) * HD_ + hd) * S_ + s] = val;
        }
      }
    }
}

// ---------------- fused RMSNorm + RoPE (in place), (b, s, h) block order ----------------
template<int LOGNH>
__global__ __launch_bounds__(256) void normrope_kernel(bf16_t* __restrict__ x,
                                                       const float* __restrict__ w,
                                                       const float* __restrict__ cosb,
                                                       const float* __restrict__ sinb,
                                                       float* __restrict__ knorm) {
  const int gid  = blockIdx.x * 4 + (threadIdx.x >> 6);  // (b, s, h) order: h innermost
  const int lane = threadIdx.x & 63;
  const int nh = 1 << LOGNH;
  const int h  = gid & (nh - 1);
  const int bs = gid >> LOGNH;                 // b*S + s
  const int b  = bs >> 11, s = bs & (S_ - 1);
  const int rowi = (b * nh + h) * S_ + s;

  bf16_t* ptr = x + (size_t)rowi * HD_ + lane * 4;
  bf16x4 xv = *(const bf16x4*)ptr;
  float v0 = (float)xv[0], v1 = (float)xv[1], v2 = (float)xv[2], v3 = (float)xv[3];
  float ss = v0 * v0 + v1 * v1 + v2 * v2 + v3 * v3;
#pragma unroll
  for (int off = 1; off < 64; off <<= 1) ss += __shfl_xor(ss, off);
  float r = rsqrtf(ss * (1.0f / HD_) + 1e-6f);

  float4 wv = *(const float4*)(w + lane * 4);
  float x0 = v0 * r * (1.0f + wv.x);
  float x1 = v1 * r * (1.0f + wv.y);
  float x2 = v2 * r * (1.0f + wv.z);
  float x3 = v3 * r * (1.0f + wv.w);

  if (knorm != nullptr) {   // row norm^2 (RoPE rotates pairs: norm preserved)
    float s2 = x0 * x0 + x1 * x1 + x2 * x2 + x3 * x3;
#pragma unroll
    for (int off = 1; off < 64; off <<= 1) s2 += __shfl_xor(s2, off);
    if (lane == 0) knorm[rowi] = s2;
  }

  float p0 = __shfl_xor(x0, 32);
  float p1 = __shfl_xor(x1, 32);
  float p2 = __shfl_xor(x2, 32);
  float p3 = __shfl_xor(x3, 32);
  float sgn = (lane < 32) ? -1.0f : 1.0f;

  float4 c  = *(const float4*)(cosb + (size_t)bs * HD_ + lane * 4);
  float4 sn = *(const float4*)(sinb + (size_t)bs * HD_ + lane * 4);
  bf16x4 o;
  o[0] = (bf16_t)(x0 * c.x + sgn * p0 * sn.x);
  o[1] = (bf16_t)(x1 * c.y + sgn * p1 * sn.y);
  o[2] = (bf16_t)(x2 * c.z + sgn * p2 * sn.z);
  o[3] = (bf16_t)(x3 * c.w + sgn * p3 * sn.w);
  *(bf16x4*)ptr = o;
}

// ---------------- per-(b,kv-head) max of knorm ----------------
__global__ __launch_bounds__(256) void kmax_reduce_kernel(const float* __restrict__ knorm,
                                                          float* __restrict__ km) {
  __shared__ float red[4];
  const int t = threadIdx.x;
  const float* src = knorm + (size_t)blockIdx.x * S_;
  float m = 0.0f;
  for (int i = t; i < S_; i += 256) m = fmaxf(m, src[i]);
#pragma unroll
  for (int off = 1; off < 64; off <<= 1) m = fmaxf(m, __shfl_xor(m, off));
  if ((t & 63) == 0) red[t >> 6] = m;
  __syncthreads();
  if (t == 0) km[blockIdx.x] = fmaxf(fmaxf(red[0], red[1]), fmaxf(red[2], red[3]));
}

// ---------------- single-pass flash attention, 4 waves x 16 q-rows, bound-based softmax ----------------
// 1-D grid of 1024 blocks, XCD-pinned: all 64 blocks of one (b,kvh) group land on one XCD
// (wgid%8 = XCD round-robin heuristic) so its 4MB K+V working set stays L2-resident.
__global__ __launch_bounds__(256, 4) void attn1p_kernel(const bf16_t* __restrict__ qb,
                                                        const bf16_t* __restrict__ kb,
                                                        const bf16_t* __restrict__ vt,
                                                        const float* __restrict__ kmaxbuf,
                                                        float* __restrict__ wout,
                                                        float* __restrict__ linv,
                                                        bf16_t* __restrict__ ctx) {
  __shared__ __align__(16) bf16_t Ks[32][264];      // +8 pad
  __shared__ __align__(16) bf16_t Vs[256][36];      // d-major, +4 pad (18-dword stride)
  __shared__ __align__(16) bf16_t p_lds[4][16][36];
  __shared__ float qn_lds[4][16];

  const int t = threadIdx.x, w = t >> 6, lane = t & 63;
  const int lr = lane & 15, lg = lane >> 4, rloc = lg * 4;

  // ---- XCD-pinned decode: g = (wgid>>9)*8 + (wgid&7); idx = (wgid>>3)&63 ----
  const int wgid = blockIdx.x;
  const int g    = ((wgid >> 9) << 3) | (wgid & 7);   // (b*NKV + kvh) group, 0..15
  const int idx  = (wgid >> 3) & 63;                  // block within group
  const int b    = g >> 3, kvh = g & 7;
  const int h    = kvh * 2 + (idx >> 5);              // GQA: 2 q-heads per group
  const int qbucket = idx & 31;
  const int bh   = b * NH_ + h;
  const int q0b  = qbucket * 64;
  const int q0   = q0b + w * 16;

  const bf16_t* qptr = qb + ((size_t)bh * S_ + q0 + lr) * HD_ + lg * 8;
  bf16x8 qf[8];
#pragma unroll
  for (int c = 0; c < 8; ++c) qf[c] = *(const bf16x8*)(qptr + c * 32);

  float qn = 0.0f;
#pragma unroll
  for (int c = 0; c < 8; ++c)
#pragma unroll
    for (int e = 0; e < 8; ++e) { float v = (float)qf[c][e]; qn += v * v; }
  qn += __shfl_xor(qn, 16);
  qn += __shfl_xor(qn, 32);
  if (lg == 0) qn_lds[w][lr] = qn;
  __syncthreads();
  const float kmax2 = kmaxbuf[b * NKV_ + kvh];
  float mb[4];
#pragma unroll
  for (int r = 0; r < 4; ++r)
    mb[r] = SCALE_ * sqrtf(qn_lds[w][rloc + r] * kmax2) + 1.0f;  // >= any score, with margin

  float l[4] = {0.f, 0.f, 0.f, 0.f};
  f32x4 oacc[16] = {};
  const int nkt = (q0b + 64) >> 5;
  float* wrow = wout + ((size_t)bh * S_ + q0) * S_;
  const bf16_t* kgb = kb + (size_t)(b * NKV_ + kvh) * S_ * HD_;
  const bf16_t* vgb = vt + (size_t)(b * NKV_ + kvh) * HD_ * S_;

  const int s_st = t >> 3, c_st = (t & 7) * 32;   // K staging: row s_st, 4x8 cols
  const int vrow = t >> 2, vcol = (t & 3) * 8;    // V staging: rows vrow+64i, 8 cols (16B)

  for (int kt = 0; kt < nkt; ++kt) {
    const int colb = kt * 32;
    __syncthreads();   // previous tile's LDS reads complete
    {  // stage K tile (32 x 256) coalesced
      const bf16_t* src = kgb + (size_t)(colb + s_st) * HD_ + c_st;
      bf16x8 k0 = *(const bf16x8*)(src);
      bf16x8 k1 = *(const bf16x8*)(src + 8);
      bf16x8 k2 = *(const bf16x8*)(src + 16);
      bf16x8 k3 = *(const bf16x8*)(src + 24);
      *(bf16x8*)&Ks[s_st][c_st]      = k0;
      *(bf16x8*)&Ks[s_st][c_st + 8]  = k1;
      *(bf16x8*)&Ks[s_st][c_st + 16] = k2;
      *(bf16x8*)&Ks[s_st][c_st + 24] = k3;
    }
#pragma unroll
    for (int i = 0; i < 4; ++i) {  // stage V tile (256 d x 32 s), 16B per lane per pass
      const int d = vrow + i * 64;
      bf16x8 vv = *(const bf16x8*)(vgb + (size_t)d * S_ + colb + vcol);
      *(bf16x8*)&Vs[d][vcol] = vv;
    }
    __syncthreads();

    if (colb <= q0 + 15) {   // wave active for this tile
      f32x4 s0 = {0.f, 0.f, 0.f, 0.f}, s1 = {0.f, 0.f, 0.f, 0.f};
#pragma unroll
      for (int c = 0; c < 8; ++c) {
        bf16x8 k0 = *(const bf16x8*)&Ks[lr][c * 32 + lg * 8];
        bf16x8 k1 = *(const bf16x8*)&Ks[16 + lr][c * 32 + lg * 8];
        s0 = __builtin_amdgcn_mfma_f32_16x16x32_bf16(qf[c], k0, s0, 0, 0, 0);
        s1 = __builtin_amdgcn_mfma_f32_16x16x32_bf16(qf[c], k1, s1, 0, 0, 0);
      }
      const int col0 = colb + lr, col1 = col0 + 16;
#pragma unroll
      for (int r = 0; r < 4; ++r) {
        const int row = q0 + rloc + r;
        const float pa = (col0 <= row) ? __expf(s0[r] * SCALE_ - mb[r]) : 0.0f;
        const float pb = (col1 <= row) ? __expf(s1[r] * SCALE_ - mb[r]) : 0.0f;
        l[r] += pa + pb;
        wrow[(size_t)(rloc + r) * S_ + col0] = pa;
        wrow[(size_t)(rloc + r) * S_ + col1] = pb;
        p_lds[w][rloc + r][lr]      = (bf16_t)pa;
        p_lds[w][rloc + r][lr + 16] = (bf16_t)pb;
      }
      bf16x8 pf = *(const bf16x8*)&p_lds[w][lr][lg * 8];   // P as A-fragment
#pragma unroll
      for (int df = 0; df < 16; ++df) {
        bf16x8 vf = *(const bf16x8*)&Vs[df * 16 + lr][lg * 8];
        oacc[df] = __builtin_amdgcn_mfma_f32_16x16x32_bf16(pf, vf, oacc[df], 0, 0, 0);
      }
    }
  }
  // row sum l across lr lanes
#pragma unroll
  for (int r = 0; r < 4; ++r) {
    l[r] += __shfl_xor(l[r], 1);
    l[r] += __shfl_xor(l[r], 2);
    l[r] += __shfl_xor(l[r], 4);
    l[r] += __shfl_xor(l[r], 8);
  }
  float invl[4];
#pragma unroll
  for (int r = 0; r < 4; ++r) invl[r] = 1.0f / l[r];

  bf16_t* cp = ctx + ((size_t)b * S_ + q0) * DQ_ + h * HD_;
#pragma unroll
  for (int df = 0; df < 16; ++df)
#pragma unroll
    for (int r = 0; r < 4; ++r)
      cp[(size_t)(rloc + r) * DQ_ + df * 16 + lr] = (bf16_t)(oacc[df][r] * invl[r]);

  if (lr == 0) {
#pragma unroll
    for (int r = 0; r < 4; ++r) linv[(size_t)bh * S_ + q0 + rloc + r] = invl[r];
  }
}

// ---------------- weights post-pass: scale lower triangle by 1/l, zero upper ----------------
__global__ __launch_bounds__(256) void wscale_kernel(float* __restrict__ wbuf,
                                                     const float* __restrict__ linv) {
  const int wv = threadIdx.x >> 6, lane = threadIdx.x & 63;
  const size_t rg = (size_t)blockIdx.x * 4 + wv;     // global row in (B*NH, S)
  const int row = (int)(rg & (S_ - 1));
  const float inv = linv[rg];
  float* base = wbuf + rg * S_;
#pragma unroll
  for (int i = 0; i < 8; ++i) {
    const int c0 = (i * 64 + lane) * 4;
    float4 v;
    if (c0 > row) {
      v = make_float4(0.f, 0.f, 0.f, 0.f);
    } else {
      v = *(const float4*)(base + c0);
      v.x = (c0 + 0 <= row) ? v.x * inv : 0.f;
      v.y = (c0 + 1 <= row) ? v.y * inv : 0.f;
      v.z = (c0 + 2 <= row) ? v.z * inv : 0.f;
      v.w = (c0 + 3 <= row) ? v.w * inv : 0.f;
    }
    *(float4*)(base + c0) = v;
  }
}

// ---------------- launch ----------------
extern "C" void kernel_launch(void* const* d_in, const int* in_sizes, int n_in,
                              void* d_out, int out_size, void* d_ws, size_t ws_size,
                              hipStream_t stream) {
  const float* hs   = (const float*)d_in[0];
  const float* cosb = (const float*)d_in[1];
  const float* sinb = (const float*)d_in[2];
  // d_in[3] attention_mask: recomputed causally in-kernel
  const float* Wq = (const float*)d_in[4];
  const float* Wk = (const float*)d_in[5];
  const float* Wv = (const float*)d_in[6];
  const float* Wo = (const float*)d_in[7];
  const float* qw = (const float*)d_in[8];
  const float* kw = (const float*)d_in[9];

  char* ws = (char*)d_ws;
  bf16_t* qb    = (bf16_t*)(ws + 0);            // 33,554,432  (B,NH,S,HD)
  bf16_t* kb    = (bf16_t*)(ws + 33554432);     // 16,777,216  (B,NKV,S,HD)
  bf16_t* vt    = (bf16_t*)(ws + 50331648);     // 16,777,216  (B,NKV,HD,S)
  bf16_t* ctx   = (bf16_t*)(ws + 67108864);     // 33,554,432  (B,S,NH*HD)
  float*  linv  = (float*)(ws + 100663296);     //    262,144
  float*  knorm = (float*)(ws + 100925440);     //    131,072
  float*  km    = (float*)(ws + 101056512);     //        128
  bf16_t* hsb   = (bf16_t*)(ws + 101056640);    // 29,360,128  (B*S, HID) bf16
  bf16_t* wqb   = (bf16_t*)(ws + 130416768);    // 29,360,128
  bf16_t* wkb   = (bf16_t*)(ws + 159776896);    // 14,680,064
  bf16_t* wvb   = (bf16_t*)(ws + 174456960);    // 14,680,064
  bf16_t* wob   = (bf16_t*)(ws + 189137024);    // 29,360,128  -> total 218,497,152

  float* out      = (float*)d_out;
  float* attn_out = out;                            // (B,S,HID) f32
  float* weights  = out + (size_t)B_ * S_ * HID_;   // (B,NH,S,S) f32

  const int M = B_ * S_;  // 4096

  // 0) one-shot bf16 conversion of activations + weights
  cvt_kernel<<<14336, 256, 0, stream>>>(hs, hsb, (B_ * S_ * HID_) / 4);
  cvt_kernel<<<14336, 256, 0, stream>>>(Wq, wqb, (DQ_ * HID_) / 4);
  cvt_kernel<<<7168,  256, 0, stream>>>(Wk, wkb, (DKV_ * HID_) / 4);
  cvt_kernel<<<7168,  256, 0, stream>>>(Wv, wvb, (DKV_ * HID_) / 4);
  cvt_kernel<<<14336, 256, 0, stream>>>(Wo, wob, (HID_ * DQ_) / 4);

  // 1) projections (bf16 x bf16, global_load_lds staging)
  gemm_lds<1><<<dim3(DQ_ / 128, M / 128), 256, 0, stream>>>(hsb, wqb, qb, M, DQ_, HID_, NH_);
  gemm_lds<1><<<dim3(DKV_ / 128, M / 128), 256, 0, stream>>>(hsb, wkb, kb, M, DKV_, HID_, NKV_);
  gemm_lds<2><<<dim3(DKV_ / 128, M / 128), 256, 0, stream>>>(hsb, wvb, vt, M, DKV_, HID_, NKV_);

  // 2) norm + rope (in place); K pass also stores per-row |k|^2
  normrope_kernel<4><<<(B_ * S_ * NH_) / 4, 256, 0, stream>>>(qb, qw, cosb, sinb, nullptr);
  normrope_kernel<3><<<(B_ * S_ * NKV_) / 4, 256, 0, stream>>>(kb, kw, cosb, sinb, knorm);
  kmax_reduce_kernel<<<B_ * NKV_, 256, 0, stream>>>(knorm, km);

  // 3) single-pass attention (unnormalized p-tilde into weights buffer), XCD-pinned grid
  attn1p_kernel<<<(S_ / 64) * (B_ * NH_), 256, 0, stream>>>(qb, kb, vt, km, weights, linv, ctx);

  // 4) weights normalization + upper-triangle zeros
  wscale_kernel<<<(B_ * NH_ * S_) / 4, 256, 0, stream>>>(weights, linv);

  // 5) output projection -> d_out (f32)
  gemm_lds<0><<<dim3(HID_ / 128, M / 128), 256, 0, stream>>>(ctx, wob, attn_out, M, HID_, DQ_, 0);
}